// Round 1
// baseline (205.613 us; speedup 1.0000x reference)
//
#include <hip/hip_runtime.h>
#include <cmath>

// CXLoss pipeline, revision 18: materialize S (bf16, 134MB in ws) — GEMM runs
// ONCE. k_gemm = R17's verified mode-0 sweep + bf16-rounded S store (colmax
// taken over the rounded values => bit-consistent with stored S). Then two
// memory-bound passes over S (LLC-resident) replace the other two GEMMs.
// R19: identical resubmit of the harness-verified 205.1 µs kernel — the
// previous bench failed on container infra (no counters); re-establishing
// baseline + profile before editing.

#define NB 4
#define CC 256
#define HW 4096
#define NQ0 8    // gemm loop-split (CMAX partials)
#define NP1 32   // pass1 p-chunks (WSUM partials)

static constexpr float kEPS = 1e-8f;
static constexpr float kSIG = 0.1f + 1e-8f;

typedef __attribute__((ext_vector_type(8)))  short short8;
typedef __attribute__((ext_vector_type(16))) float f32x16;

// workspace layout (float units)
enum {
  OFF_MEAN = 0,                        // 256 channel means
  OFF_CMAX = 256,                      // NQ0*NB*HW colmax partials
  OFF_WSUM = OFF_CMAX + NQ0*NB*HW,     // NP1*NB*HW Wsum partials
  OFF_MAXV = OFF_WSUM + NP1*NB*HW,     // NB*HW maxv (direct)
  OFF_GB   = OFF_MAXV + NB*HW,         // gamma[NB*HW], beta[NB*HW]
  OFF_GT   = OFF_GB + 2*NB*HW,         // NB*HW*CC bf16, fragment-tiled
  OFF_GI   = OFF_GT + NB*HW*CC/2,
  OFF_S    = OFF_GI + NB*HW*CC/2,      // NB*HW*HW bf16  (134 MB)
  WS_FLOATS_FULL = OFF_S + NB*HW*HW/2
};

__device__ __forceinline__ ushort cvt_bf16(float x) {
  unsigned u = __float_as_uint(x);
  unsigned r = (u + 0x7fffu + ((u >> 16) & 1u)) >> 16;  // round-nearest-even
  return (ushort)r;
}
__device__ __forceinline__ float bf2f(ushort u) {
  return __uint_as_float((unsigned)u << 16);
}

__device__ __forceinline__ float blockSum256(float v) {
  __shared__ float sh[4];
  const int lane = threadIdx.x & 63, wv = threadIdx.x >> 6;
  #pragma unroll
  for (int o = 32; o > 0; o >>= 1) v += __shfl_down(v, o, 64);
  __syncthreads();
  if (lane == 0) sh[wv] = v;
  __syncthreads();
  return sh[0] + sh[1] + sh[2] + sh[3];
}

// K1: per-channel mean of featureT. grid=256
__global__ __launch_bounds__(256) void k_mean9(const float* __restrict__ fT,
                                               float* __restrict__ ws) {
  const int c = blockIdx.x, t = threadIdx.x;
  float s = 0.f;
  for (int n = 0; n < NB; ++n) {
    const float* p = fT + (size_t)(n*CC + c)*HW;
    #pragma unroll
    for (int k = 0; k < 16; ++k) s += p[k*256 + t];
  }
  const float tot = blockSum256(s);
  if (t == 0) ws[OFF_MEAN + c] = tot * (1.0f/16384.0f);
}

// K2: fused normalize + fragment-tiled bf16 write (verified R14 layout):
// offset_ushort(n, r32, kc) = ((n*128 + r32)*16 + kc)*512 + l*8
//   holds X[n][p = r32*32 + (l&31)][c = kc*16 + (l>>5)*8 + j], j<8.
// grid = 2 * NB * 128 = 1024 blocks.
__global__ __launch_bounds__(256) void k_prep9(const float* __restrict__ fT,
                                               const float* __restrict__ fI,
                                               float* __restrict__ ws) {
  __shared__ float stage[32][257];
  __shared__ float prt[8][32];
  __shared__ float sinv[32];
  const int t = threadIdx.x, l = t & 63;
  int bid = blockIdx.x;
  const int tensor = (bid >= 512); bid &= 511;
  const int n   = bid >> 7;
  const int r32 = bid & 127;
  const int p0  = r32 * 32;

  const float* __restrict__ src = tensor ? fI : fT;
  ushort* __restrict__ dst = (ushort*)(ws + (tensor ? OFF_GI : OFF_GT));
  const float* __restrict__ mean = ws + OFF_MEAN;

  const int pl = t & 31, cg = t >> 5;
  float acc = 0.f;
  #pragma unroll
  for (int i = 0; i < 32; ++i) {
    const int c = cg*32 + i;
    const float v = src[((size_t)(n*CC + c))*HW + p0 + pl] - mean[c];
    stage[pl][c] = v;
    acc += v*v;
  }
  prt[cg][pl] = acc;
  __syncthreads();
  if (t < 32) {
    float s = 0.f;
    #pragma unroll
    for (int g = 0; g < 8; ++g) s += prt[g][t];
    sinv[t] = 1.0f/(sqrtf(s) + kEPS);
  }
  __syncthreads();

  const int w = t >> 6, lhi = l >> 5, m = l & 31;
  const float iv = sinv[m];
  #pragma unroll
  for (int i = 0; i < 4; ++i) {
    const int kc = w*4 + i;
    const int cb = kc*16 + lhi*8;
    short8 o;
    #pragma unroll
    for (int j = 0; j < 8; ++j)
      ((ushort*)&o)[j] = cvt_bf16(stage[m][cb + j] * iv);
    *(short8*)(dst + (((size_t)(n*128 + r32)*16 + kc) << 9) + l*8) = o;
  }
}

// K3: single GEMM sweep (R17 mode-0 structure) + bf16 S store + colmax.
// grid = NB*32strips*NQ0 = 1024 blocks, 4 blocks/CU.
__global__ __launch_bounds__(256, 4) void k_gemm9(
    const ushort* __restrict__ gA, const ushort* __restrict__ gB,
    float* __restrict__ ws)
{
  __shared__ ushort Ab[2][8192];     // double-buffered 32-row A tile (16KB)
  __shared__ float red2[128];

  const int t = threadIdx.x;
  const int w = t >> 6, l = t & 63;
  const int ln31 = l & 31, lhi = l >> 5;

  const int b = blockIdx.x;
  const int h = b & 7, sid = b >> 3;
  const int n = sid >> 5;
  const int col0 = (sid & 31) * 128;

  const ushort* __restrict__ gAn = gA + (size_t)(n*128 + h*16)*8192;

  // prologue staging: tile0 -> Ab[0]; tile1 -> pf
  short8 pf[4];
  #pragma unroll
  for (int i = 0; i < 4; ++i)
    pf[i] = *(const short8*)(gAn + (size_t)(i*256 + t)*8);
  #pragma unroll
  for (int i = 0; i < 4; ++i)
    *(short8*)&Ab[0][(i*256 + t)*8] = pf[i];
  #pragma unroll
  for (int i = 0; i < 4; ++i)
    pf[i] = *(const short8*)(gAn + 8192 + (size_t)(i*256 + t)*8);

  // B fragments: wave w owns col-tile RB
  const int RB = (col0 >> 5) + w;
  short8 breg[16];
  #pragma unroll
  for (int kc = 0; kc < 16; ++kc)
    breg[kc] = *(const short8*)(gB +
        (((size_t)(n*128 + RB)*16 + kc) << 9) + l*8);

  const int qc = col0 + w*32 + ln31;
  ushort* __restrict__ Sq = (ushort*)(ws + OFF_S) + (size_t)n*HW*HW + qc;

  float runl = -3.0e38f;

  for (int iter = 0; iter < 16; ++iter) {
    const int p = iter & 1;
    __syncthreads();
    if (iter + 1 < 16) {
      #pragma unroll
      for (int i = 0; i < 4; ++i)
        *(short8*)&Ab[p^1][(i*256 + t)*8] = pf[i];
      if (iter + 2 < 16) {
        const ushort* __restrict__ src = gAn + (size_t)(iter + 2)*8192;
        #pragma unroll
        for (int i = 0; i < 4; ++i)
          pf[i] = *(const short8*)(src + (size_t)(i*256 + t)*8);
      }
    }

    f32x16 acc;
    #pragma unroll
    for (int e = 0; e < 16; ++e) acc[e] = 0.f;
    #pragma unroll
    for (int kc = 0; kc < 16; ++kc) {
      const short8 a0 = *(const short8*)&Ab[p][kc*512 + l*8];
      acc = __builtin_amdgcn_mfma_f32_32x32x16_bf16(a0, breg[kc], acc, 0, 0, 0);
    }

    // epilogue: round->store S, colmax over ROUNDED values (consistency).
    // C/D map: col = lane&31, row = (reg&3) + 8*(reg>>2) + 4*(lane>>5)
    const int pb = h*512 + iter*32 + 4*lhi;
    #pragma unroll
    for (int r = 0; r < 16; ++r) {
      const int prow = pb + (r & 3) + 8*(r >> 2);
      const ushort u = cvt_bf16(acc[r]);
      Sq[(size_t)prow * HW] = u;
      runl = fmaxf(runl, bf2f(u));
    }
  }

  {
    const float o = __shfl_xor(runl, 32, 64);
    runl = fmaxf(runl, o);
  }
  if (l < 32) red2[w*32 + ln31] = runl;
  __syncthreads();
  if (t < 128)
    ws[OFF_CMAX + h*(NB*HW) + n*HW + col0 + t] = red2[t];
}

// K4: pass1 — Wsum partials. block: (n, qblk of 512, pchunk of 128).
// grid = 4 * 8 * 32 = 1024. thread t owns q = qblk*512 + 2t (+0,+1).
__global__ __launch_bounds__(256) void k_pass1(float* __restrict__ ws) {
  const int t = threadIdx.x;
  const int b = blockIdx.x;
  const int pc = b & 31, rest = b >> 5;
  const int n = rest >> 3, qblk = rest & 7;
  const int q = qblk*512 + 2*t;

  float a0, b0, a1, b1;
  {
    float cm0 = -3.0e38f, cm1 = -3.0e38f;
    #pragma unroll
    for (int hh = 0; hh < NQ0; ++hh) {
      cm0 = fmaxf(cm0, ws[OFF_CMAX + hh*(NB*HW) + n*HW + q]);
      cm1 = fmaxf(cm1, ws[OFF_CMAX + hh*(NB*HW) + n*HW + q + 1]);
    }
    const float i0 = 1.0f/(2.0f*(0.5f*(1.0f - cm0) + kEPS));
    const float i1 = 1.0f/(2.0f*(0.5f*(1.0f - cm1) + kEPS));
    b0 = i0 / kSIG; a0 = (1.0f - i0) / kSIG;
    b1 = i1 / kSIG; a1 = (1.0f - i1) / kSIG;
  }

  const ushort* __restrict__ S =
      (const ushort*)(ws + OFF_S) + (size_t)n*HW*HW + q;
  float acc0 = 0.f, acc1 = 0.f;
  const int p0 = pc*128;
  #pragma unroll 8
  for (int i = 0; i < 128; ++i) {
    const ushort2 u = *(const ushort2*)(S + (size_t)(p0 + i)*HW);
    acc0 += __expf(fmaf(b0, bf2f(u.x), a0));
    acc1 += __expf(fmaf(b1, bf2f(u.y), a1));
  }
  float2 o; o.x = acc0; o.y = acc1;
  *(float2*)&ws[OFF_WSUM + pc*(NB*HW) + n*HW + q] = o;
}

// K5: gamma/beta arrays. grid = 64 (NB*HW/256).
__global__ __launch_bounds__(256) void k_gb9(float* __restrict__ ws) {
  const int idx = blockIdx.x*256 + threadIdx.x;   // n*HW + q
  float cm = -3.0e38f;
  #pragma unroll
  for (int hh = 0; hh < NQ0; ++hh)
    cm = fmaxf(cm, ws[OFF_CMAX + hh*(NB*HW) + idx]);
  const float inv2d = 1.0f/(2.0f*(0.5f*(1.0f - cm) + kEPS));
  const float beta  = inv2d / kSIG;
  const float alpha = (1.0f - inv2d) / kSIG;
  float sw = 0.f;
  #pragma unroll
  for (int pc = 0; pc < NP1; ++pc)
    sw += ws[OFF_WSUM + pc*(NB*HW) + idx];
  ws[OFF_GB + idx]         = alpha - logf(sw + kEPS);  // gamma
  ws[OFF_GB + NB*HW + idx] = beta;
}

// K6: pass2 — maxv[n][p] = max_q (gamma_q + beta_q * s[p][q]).
// grid = NB * 256 = 1024; block owns 16 p-rows; gamma/beta staged in LDS.
__global__ __launch_bounds__(256) void k_pass2(float* __restrict__ ws) {
  __shared__ float gq[4096], bq[4096];
  const int t = threadIdx.x, w = t >> 6, l = t & 63;
  const int b = blockIdx.x;
  const int n = b >> 8, pg = b & 255;

  const float* __restrict__ G  = ws + OFF_GB + n*HW;
  const float* __restrict__ Bq = ws + OFF_GB + NB*HW + n*HW;
  #pragma unroll
  for (int i = 0; i < 4; ++i) {
    *(float4*)&gq[(i*256 + t)*4] = *(const float4*)&G [(i*256 + t)*4];
    *(float4*)&bq[(i*256 + t)*4] = *(const float4*)&Bq[(i*256 + t)*4];
  }
  __syncthreads();

  const ushort* __restrict__ S =
      (const ushort*)(ws + OFF_S) + (size_t)n*HW*HW;
  #pragma unroll
  for (int r = 0; r < 4; ++r) {
    const int p = pg*16 + w*4 + r;
    const ushort* __restrict__ row = S + (size_t)p*HW;
    float m = -3.0e38f;
    #pragma unroll 4
    for (int it = 0; it < 32; ++it) {
      const int q = it*128 + 2*l;
      const ushort2 u = *(const ushort2*)(row + q);
      m = fmaxf(m, fmaf(bq[q],     bf2f(u.x), gq[q]));
      m = fmaxf(m, fmaf(bq[q + 1], bf2f(u.y), gq[q + 1]));
    }
    #pragma unroll
    for (int o = 32; o > 0; o >>= 1) m = fmaxf(m, __shfl_xor(m, o, 64));
    if (l == 0) ws[OFF_MAXV + n*HW + p] = m;
  }
}

// K7: final loss. one block.
__global__ __launch_bounds__(256) void k_final9(const float* __restrict__ ws,
                                                float* __restrict__ out) {
  const int t = threadIdx.x;
  float loss = 0.f;
  for (int n = 0; n < NB; ++n) {
    float s = 0.f;
    for (int k = 0; k < 16; ++k)
      s += __expf(ws[OFF_MAXV + n*HW + k*256 + t]);
    const float tot = blockSum256(s);
    loss += -logf(tot*(1.0f/4096.0f) + kEPS);
  }
  if (t == 0) out[0] = loss*0.25f;
}

extern "C" void kernel_launch(void* const* d_in, const int* in_sizes, int n_in,
                              void* d_out, int out_size, void* d_ws, size_t ws_size,
                              hipStream_t stream) {
  const float* fT = (const float*)d_in[0];
  const float* fI = (const float*)d_in[1];
  float* out = (float*)d_out;
  float* ws  = (float*)d_ws;

  const size_t need_full = (size_t)WS_FLOATS_FULL * sizeof(float);
  if (ws_size < need_full) return;  // ws measured 256 MB (R2); need ~154 MB

  const ushort* GT = (const ushort*)(ws + OFF_GT);
  const ushort* GI = (const ushort*)(ws + OFF_GI);
  k_mean9 <<<256,  256, 0, stream>>>(fT, ws);
  k_prep9 <<<1024, 256, 0, stream>>>(fT, fI, ws);
  k_gemm9 <<<1024, 256, 0, stream>>>(GT, GI, ws);   // S + colmax partials
  k_pass1 <<<1024, 256, 0, stream>>>(ws);           // Wsum partials
  k_gb9   <<<64,   256, 0, stream>>>(ws);           // gamma/beta arrays
  k_pass2 <<<1024, 256, 0, stream>>>(ws);           // maxv
  k_final9<<<1,    256, 0, stream>>>(ws, out);
}

// Round 2
// 176.499 us; speedup vs baseline: 1.1649x; 1.1649x over previous
//
#include <hip/hip_runtime.h>
#include <cmath>

// CXLoss pipeline, revision 20: k_gemm epilogue restructured.
// R19 profile: k_gemm9 = 81.3us, MfmaUtil 16.5%, VALUBusy 14.7%, HBM 35% --
// latency-bound on 16 scattered 2B stores/wave/iter; WRITE 167.8MB (+25% RMW),
// FETCH 56.8MB (+36MB partial-line fills).
// Fix: block-wide LDS transpose epilogue (Eb[32][136] bf16) -> 2 coalesced
// dwordx4 stores/thread/iter (256B-contiguous rows, full 128B lines).
// A tile single-buffered (pf regs are the double buffer); 3 barriers/iter.
// LDS 25.6KB -> still 4 blocks/CU. Colmax unchanged (rounded values, lane=q).

#define NB 4
#define CC 256
#define HW 4096
#define NQ0 8    // gemm loop-split (CMAX partials)
#define NP1 32   // pass1 p-chunks (WSUM partials)

static constexpr float kEPS = 1e-8f;
static constexpr float kSIG = 0.1f + 1e-8f;

typedef __attribute__((ext_vector_type(8)))  short short8;
typedef __attribute__((ext_vector_type(16))) float f32x16;

// workspace layout (float units)
enum {
  OFF_MEAN = 0,                        // 256 channel means
  OFF_CMAX = 256,                      // NQ0*NB*HW colmax partials
  OFF_WSUM = OFF_CMAX + NQ0*NB*HW,     // NP1*NB*HW Wsum partials
  OFF_MAXV = OFF_WSUM + NP1*NB*HW,     // NB*HW maxv (direct)
  OFF_GB   = OFF_MAXV + NB*HW,         // gamma[NB*HW], beta[NB*HW]
  OFF_GT   = OFF_GB + 2*NB*HW,         // NB*HW*CC bf16, fragment-tiled
  OFF_GI   = OFF_GT + NB*HW*CC/2,
  OFF_S    = OFF_GI + NB*HW*CC/2,      // NB*HW*HW bf16  (134 MB)
  WS_FLOATS_FULL = OFF_S + NB*HW*HW/2
};

__device__ __forceinline__ ushort cvt_bf16(float x) {
  unsigned u = __float_as_uint(x);
  unsigned r = (u + 0x7fffu + ((u >> 16) & 1u)) >> 16;  // round-nearest-even
  return (ushort)r;
}
__device__ __forceinline__ float bf2f(ushort u) {
  return __uint_as_float((unsigned)u << 16);
}

__device__ __forceinline__ float blockSum256(float v) {
  __shared__ float sh[4];
  const int lane = threadIdx.x & 63, wv = threadIdx.x >> 6;
  #pragma unroll
  for (int o = 32; o > 0; o >>= 1) v += __shfl_down(v, o, 64);
  __syncthreads();
  if (lane == 0) sh[wv] = v;
  __syncthreads();
  return sh[0] + sh[1] + sh[2] + sh[3];
}

// K1: per-channel mean of featureT. grid=256
__global__ __launch_bounds__(256) void k_mean9(const float* __restrict__ fT,
                                               float* __restrict__ ws) {
  const int c = blockIdx.x, t = threadIdx.x;
  float s = 0.f;
  for (int n = 0; n < NB; ++n) {
    const float* p = fT + (size_t)(n*CC + c)*HW;
    #pragma unroll
    for (int k = 0; k < 16; ++k) s += p[k*256 + t];
  }
  const float tot = blockSum256(s);
  if (t == 0) ws[OFF_MEAN + c] = tot * (1.0f/16384.0f);
}

// K2: fused normalize + fragment-tiled bf16 write (verified R14 layout):
// offset_ushort(n, r32, kc) = ((n*128 + r32)*16 + kc)*512 + l*8
//   holds X[n][p = r32*32 + (l&31)][c = kc*16 + (l>>5)*8 + j], j<8.
// grid = 2 * NB * 128 = 1024 blocks.
__global__ __launch_bounds__(256) void k_prep9(const float* __restrict__ fT,
                                               const float* __restrict__ fI,
                                               float* __restrict__ ws) {
  __shared__ float stage[32][257];
  __shared__ float prt[8][32];
  __shared__ float sinv[32];
  const int t = threadIdx.x, l = t & 63;
  int bid = blockIdx.x;
  const int tensor = (bid >= 512); bid &= 511;
  const int n   = bid >> 7;
  const int r32 = bid & 127;
  const int p0  = r32 * 32;

  const float* __restrict__ src = tensor ? fI : fT;
  ushort* __restrict__ dst = (ushort*)(ws + (tensor ? OFF_GI : OFF_GT));
  const float* __restrict__ mean = ws + OFF_MEAN;

  const int pl = t & 31, cg = t >> 5;
  float acc = 0.f;
  #pragma unroll
  for (int i = 0; i < 32; ++i) {
    const int c = cg*32 + i;
    const float v = src[((size_t)(n*CC + c))*HW + p0 + pl] - mean[c];
    stage[pl][c] = v;
    acc += v*v;
  }
  prt[cg][pl] = acc;
  __syncthreads();
  if (t < 32) {
    float s = 0.f;
    #pragma unroll
    for (int g = 0; g < 8; ++g) s += prt[g][t];
    sinv[t] = 1.0f/(sqrtf(s) + kEPS);
  }
  __syncthreads();

  const int w = t >> 6, lhi = l >> 5, m = l & 31;
  const float iv = sinv[m];
  #pragma unroll
  for (int i = 0; i < 4; ++i) {
    const int kc = w*4 + i;
    const int cb = kc*16 + lhi*8;
    short8 o;
    #pragma unroll
    for (int j = 0; j < 8; ++j)
      ((ushort*)&o)[j] = cvt_bf16(stage[m][cb + j] * iv);
    *(short8*)(dst + (((size_t)(n*128 + r32)*16 + kc) << 9) + l*8) = o;
  }
}

// K3: single GEMM sweep + bf16 S store (LDS-transposed, coalesced) + colmax.
// grid = NB*32strips*NQ0 = 1024 blocks, 4 blocks/CU.
__global__ __launch_bounds__(256, 4) void k_gemm9(
    const ushort* __restrict__ gA, const ushort* __restrict__ gB,
    float* __restrict__ ws)
{
  __shared__ ushort Ab[8192];        // single-buffered 32-row A tile (16KB)
  __shared__ ushort Eb[32*136];      // epilogue transpose buffer (8.5KB, pad 8)
  __shared__ float red2[128];

  const int t = threadIdx.x;
  const int w = t >> 6, l = t & 63;
  const int ln31 = l & 31, lhi = l >> 5;

  const int b = blockIdx.x;
  const int h = b & 7, sid = b >> 3;
  const int n = sid >> 5;
  const int col0 = (sid & 31) * 128;

  const ushort* __restrict__ gAn = gA + (size_t)(n*128 + h*16)*8192;

  // prologue: pf <- tile 0 (register prefetch is the double buffer)
  short8 pf[4];
  #pragma unroll
  for (int i = 0; i < 4; ++i)
    pf[i] = *(const short8*)(gAn + (size_t)(i*256 + t)*8);

  // B fragments: wave w owns col-tile RB
  const int RB = (col0 >> 5) + w;
  short8 breg[16];
  #pragma unroll
  for (int kc = 0; kc < 16; ++kc)
    breg[kc] = *(const short8*)(gB +
        (((size_t)(n*128 + RB)*16 + kc) << 9) + l*8);

  ushort* __restrict__ Sn = (ushort*)(ws + OFF_S) + (size_t)n*HW*HW;

  const int ecol = w*32 + ln31;      // this lane's q column within Eb (0..127)
  const int rrow = t >> 4;           // read-back row 0..15 (+16*k)
  const int rq   = (t & 15) * 8;     // read-back q offset (ushorts)

  float runl = -3.0e38f;

  for (int iter = 0; iter < 16; ++iter) {
    __syncthreads();                 // Eb reads (i-1) + MFMA (i-1) complete
    #pragma unroll
    for (int i = 0; i < 4; ++i)
      *(short8*)&Ab[(i*256 + t)*8] = pf[i];
    if (iter + 1 < 16) {
      const ushort* __restrict__ src = gAn + (size_t)(iter + 1)*8192;
      #pragma unroll
      for (int i = 0; i < 4; ++i)
        pf[i] = *(const short8*)(src + (size_t)(i*256 + t)*8);
    }
    __syncthreads();                 // Ab staged

    f32x16 acc;
    #pragma unroll
    for (int e = 0; e < 16; ++e) acc[e] = 0.f;
    #pragma unroll
    for (int kc = 0; kc < 16; ++kc) {
      const short8 a0 = *(const short8*)&Ab[kc*512 + l*8];
      acc = __builtin_amdgcn_mfma_f32_32x32x16_bf16(a0, breg[kc], acc, 0, 0, 0);
    }

    // round -> colmax over ROUNDED values (bit-consistent) -> stage into Eb.
    // C/D map: col = lane&31 (q), row = (reg&3) + 8*(reg>>2) + 4*(lane>>5)
    #pragma unroll
    for (int r = 0; r < 16; ++r) {
      const int lrow = 4*lhi + (r & 3) + 8*(r >> 2);   // 0..31
      const ushort u = cvt_bf16(acc[r]);
      Eb[lrow*136 + ecol] = u;
      runl = fmaxf(runl, bf2f(u));
    }
    __syncthreads();                 // Eb staged

    // coalesced wide store: 2 x 16B per thread; 256B contiguous per row.
    const int pb = h*512 + iter*32;
    #pragma unroll
    for (int k = 0; k < 2; ++k) {
      const int lr = rrow + 16*k;
      const short8 v = *(const short8*)&Eb[lr*136 + rq];
      *(short8*)(Sn + (size_t)(pb + lr)*HW + col0 + rq) = v;
    }
  }

  {
    const float o = __shfl_xor(runl, 32, 64);
    runl = fmaxf(runl, o);
  }
  if (l < 32) red2[w*32 + ln31] = runl;
  __syncthreads();
  if (t < 128)
    ws[OFF_CMAX + h*(NB*HW) + n*HW + col0 + t] = red2[t];
}

// K4: pass1 — Wsum partials. block: (n, qblk of 512, pchunk of 128).
// grid = 4 * 8 * 32 = 1024. thread t owns q = qblk*512 + 2t (+0,+1).
__global__ __launch_bounds__(256) void k_pass1(float* __restrict__ ws) {
  const int t = threadIdx.x;
  const int b = blockIdx.x;
  const int pc = b & 31, rest = b >> 5;
  const int n = rest >> 3, qblk = rest & 7;
  const int q = qblk*512 + 2*t;

  float a0, b0, a1, b1;
  {
    float cm0 = -3.0e38f, cm1 = -3.0e38f;
    #pragma unroll
    for (int hh = 0; hh < NQ0; ++hh) {
      cm0 = fmaxf(cm0, ws[OFF_CMAX + hh*(NB*HW) + n*HW + q]);
      cm1 = fmaxf(cm1, ws[OFF_CMAX + hh*(NB*HW) + n*HW + q + 1]);
    }
    const float i0 = 1.0f/(2.0f*(0.5f*(1.0f - cm0) + kEPS));
    const float i1 = 1.0f/(2.0f*(0.5f*(1.0f - cm1) + kEPS));
    b0 = i0 / kSIG; a0 = (1.0f - i0) / kSIG;
    b1 = i1 / kSIG; a1 = (1.0f - i1) / kSIG;
  }

  const ushort* __restrict__ S =
      (const ushort*)(ws + OFF_S) + (size_t)n*HW*HW + q;
  float acc0 = 0.f, acc1 = 0.f;
  const int p0 = pc*128;
  #pragma unroll 8
  for (int i = 0; i < 128; ++i) {
    const ushort2 u = *(const ushort2*)(S + (size_t)(p0 + i)*HW);
    acc0 += __expf(fmaf(b0, bf2f(u.x), a0));
    acc1 += __expf(fmaf(b1, bf2f(u.y), a1));
  }
  float2 o; o.x = acc0; o.y = acc1;
  *(float2*)&ws[OFF_WSUM + pc*(NB*HW) + n*HW + q] = o;
}

// K5: gamma/beta arrays. grid = 64 (NB*HW/256).
__global__ __launch_bounds__(256) void k_gb9(float* __restrict__ ws) {
  const int idx = blockIdx.x*256 + threadIdx.x;   // n*HW + q
  float cm = -3.0e38f;
  #pragma unroll
  for (int hh = 0; hh < NQ0; ++hh)
    cm = fmaxf(cm, ws[OFF_CMAX + hh*(NB*HW) + idx]);
  const float inv2d = 1.0f/(2.0f*(0.5f*(1.0f - cm) + kEPS));
  const float beta  = inv2d / kSIG;
  const float alpha = (1.0f - inv2d) / kSIG;
  float sw = 0.f;
  #pragma unroll
  for (int pc = 0; pc < NP1; ++pc)
    sw += ws[OFF_WSUM + pc*(NB*HW) + idx];
  ws[OFF_GB + idx]         = alpha - logf(sw + kEPS);  // gamma
  ws[OFF_GB + NB*HW + idx] = beta;
}

// K6: pass2 — maxv[n][p] = max_q (gamma_q + beta_q * s[p][q]).
// grid = NB * 256 = 1024; block owns 16 p-rows; gamma/beta staged in LDS.
__global__ __launch_bounds__(256) void k_pass2(float* __restrict__ ws) {
  __shared__ float gq[4096], bq[4096];
  const int t = threadIdx.x, w = t >> 6, l = t & 63;
  const int b = blockIdx.x;
  const int n = b >> 8, pg = b & 255;

  const float* __restrict__ G  = ws + OFF_GB + n*HW;
  const float* __restrict__ Bq = ws + OFF_GB + NB*HW + n*HW;
  #pragma unroll
  for (int i = 0; i < 4; ++i) {
    *(float4*)&gq[(i*256 + t)*4] = *(const float4*)&G [(i*256 + t)*4];
    *(float4*)&bq[(i*256 + t)*4] = *(const float4*)&Bq[(i*256 + t)*4];
  }
  __syncthreads();

  const ushort* __restrict__ S =
      (const ushort*)(ws + OFF_S) + (size_t)n*HW*HW;
  #pragma unroll
  for (int r = 0; r < 4; ++r) {
    const int p = pg*16 + w*4 + r;
    const ushort* __restrict__ row = S + (size_t)p*HW;
    float m = -3.0e38f;
    #pragma unroll 4
    for (int it = 0; it < 32; ++it) {
      const int q = it*128 + 2*l;
      const ushort2 u = *(const ushort2*)(row + q);
      m = fmaxf(m, fmaf(bq[q],     bf2f(u.x), gq[q]));
      m = fmaxf(m, fmaf(bq[q + 1], bf2f(u.y), gq[q + 1]));
    }
    #pragma unroll
    for (int o = 32; o > 0; o >>= 1) m = fmaxf(m, __shfl_xor(m, o, 64));
    if (l == 0) ws[OFF_MAXV + n*HW + p] = m;
  }
}

// K7: final loss. one block.
__global__ __launch_bounds__(256) void k_final9(const float* __restrict__ ws,
                                                float* __restrict__ out) {
  const int t = threadIdx.x;
  float loss = 0.f;
  for (int n = 0; n < NB; ++n) {
    float s = 0.f;
    for (int k = 0; k < 16; ++k)
      s += __expf(ws[OFF_MAXV + n*HW + k*256 + t]);
    const float tot = blockSum256(s);
    loss += -logf(tot*(1.0f/4096.0f) + kEPS);
  }
  if (t == 0) out[0] = loss*0.25f;
}

extern "C" void kernel_launch(void* const* d_in, const int* in_sizes, int n_in,
                              void* d_out, int out_size, void* d_ws, size_t ws_size,
                              hipStream_t stream) {
  const float* fT = (const float*)d_in[0];
  const float* fI = (const float*)d_in[1];
  float* out = (float*)d_out;
  float* ws  = (float*)d_ws;

  const size_t need_full = (size_t)WS_FLOATS_FULL * sizeof(float);
  if (ws_size < need_full) return;  // ws measured 256 MB (R2); need ~154 MB

  const ushort* GT = (const ushort*)(ws + OFF_GT);
  const ushort* GI = (const ushort*)(ws + OFF_GI);
  k_mean9 <<<256,  256, 0, stream>>>(fT, ws);
  k_prep9 <<<1024, 256, 0, stream>>>(fT, fI, ws);
  k_gemm9 <<<1024, 256, 0, stream>>>(GT, GI, ws);   // S + colmax partials
  k_pass1 <<<1024, 256, 0, stream>>>(ws);           // Wsum partials
  k_gb9   <<<64,   256, 0, stream>>>(ws);           // gamma/beta arrays
  k_pass2 <<<1024, 256, 0, stream>>>(ws);           // maxv
  k_final9<<<1,    256, 0, stream>>>(ws, out);
}